// Round 4
// baseline (216.993 us; speedup 1.0000x reference)
//
#include <hip/hip_runtime.h>
#include <hip/hip_bf16.h>

#define N_NODES 50000
#define N_EDGES 800000
#define EP (N_EDGES + N_NODES)   // with self-loops
#define IN_C 128
#define HID 64
#define HEADS 2
#define LAT 32
#define NEG_SLOPE 0.2f
#define MAXDEG 256     // max in-degree for agg2 LDS; deg = 1 + Poisson(16)
#define MAXDEG1 96     // agg1 fused kernel: P(Poisson(16) > 95) ~ e^-90
#define NBUCKET 391    // ceil(N_NODES/128): coarse dst-buckets of 128 nodes
#define BCAP 3072      // bucket capacity; expect ~2176 +- 47 (20 sigma margin)
#define CHUNK 2048     // edges per scatter block (18KB LDS -> 8 blocks/CU)
#define NSCAT ((EP + CHUNK - 1) / CHUNK)   // 416 scatter blocks
#define NPROJ1 ((N_NODES + 31) / 32)       // 1563 proj1 blocks

typedef __attribute__((ext_vector_type(8))) short bf16x8;
typedef __attribute__((ext_vector_type(4))) float f32x4;

// fp32 -> bf16 round-to-nearest-even
__device__ __forceinline__ unsigned short f2bf(float f) {
  unsigned u = __float_as_uint(f);
  u += 0x7FFF + ((u >> 16) & 1);
  return (unsigned short)(u >> 16);
}
__device__ __forceinline__ float bf_lo(unsigned u) { return __uint_as_float(u << 16); }
__device__ __forceinline__ float bf_hi(unsigned u) { return __uint_as_float(u & 0xFFFF0000u); }

__device__ __forceinline__ bf16x8 pack_bf8(const float* __restrict__ p) {
  float4 a = *(const float4*)p;
  float4 b = *(const float4*)(p + 4);
  bf16x8 r;
  r[0] = (short)f2bf(a.x); r[1] = (short)f2bf(a.y);
  r[2] = (short)f2bf(a.z); r[3] = (short)f2bf(a.w);
  r[4] = (short)f2bf(b.x); r[5] = (short)f2bf(b.y);
  r[6] = (short)f2bf(b.z); r[7] = (short)f2bf(b.w);
  return r;
}

// ======= prep: zero cursors + pack W1/[Wmu|Wlv] into B-fragment layout ======
// Wb layout: [(kk*4+quad)*N + n]*8 + j  holds  W[k = kk*32+quad*8+j][n]
__global__ __launch_bounds__(256) void prep_kernel(
    const float* __restrict__ W1, const float* __restrict__ Wmu,
    const float* __restrict__ Wlv, int* __restrict__ cursor,
    unsigned short* __restrict__ Wb1g, unsigned short* __restrict__ Wb2g) {
  const int b = blockIdx.x, t = threadIdx.x;
  if (b == 0) {
    for (int i = t; i < NBUCKET; i += 256) cursor[i] = 0;
  } else if (b <= 64) {
    int i = (b - 1) * 256 + t;       // [0, 16384)
    int k = i >> 7, n = i & 127;
    int kk = k >> 5, q = (k >> 3) & 3, j = k & 7;
    Wb1g[((((kk << 2) + q) << 7) + n) * 8 + j] = f2bf(W1[i]);
  } else {
    int i = (b - 65) * 256 + t;      // [0, 8192)
    int k = i >> 6, n = i & 63;
    float v = (n < 32) ? Wmu[k * 32 + n] : Wlv[k * 32 + (n - 32)];
    int kk = k >> 5, q = (k >> 3) & 3, j = k & 7;
    Wb2g[((((kk << 2) + q) << 6) + n) * 8 + j] = f2bf(v);
  }
}

// ---------------- K1 shared-memory overlay (scatter | proj1) ----------------
struct ScatSmem {
  int histL[512];
  int baseL[512];
  int gbaseL[512];
  int wsumS[4];
  int nvalS;
  unsigned staging[CHUNK];
  unsigned short bktidL[CHUNK];
};
union K1Smem { ScatSmem sc; float part[32][4]; };

// ================= K1: bucket_scatter (blocks 0..NSCAT) =====================
// =================     proj1 (MFMA, global B-frags) + fused a1 ==============
__global__ __launch_bounds__(256) void k1_kernel(
    const int* __restrict__ ei, int* __restrict__ cursor,
    unsigned* __restrict__ csr,
    const float* __restrict__ x, const unsigned short* __restrict__ Wb1g,
    const float* __restrict__ att_src, const float* __restrict__ att_dst,
    unsigned short* __restrict__ h1b, float* __restrict__ a1) {
  __shared__ K1Smem sm;
  const int t = threadIdx.x, lane = t & 63, wid = t >> 6;

  if (blockIdx.x < NSCAT) {
    // ---------------- bucket scatter: LDS binning, chunked global writes ----
    for (int i = t; i < 512; i += 256) sm.sc.histL[i] = 0;
    __syncthreads();
    int myb[CHUNK / 256];
    int myloc[CHUNK / 256];
    unsigned mypay[CHUNK / 256];
    #pragma unroll
    for (int i = 0; i < CHUNK / 256; ++i) {
      int e = blockIdx.x * CHUNK + i * 256 + t;
      if (e < EP) {
        int s, d;
        if (e < N_EDGES) { s = ei[e]; d = ei[N_EDGES + e]; }
        else { s = d = e - N_EDGES; }
        int b = d >> 7;
        myb[i] = b;
        mypay[i] = ((unsigned)(d & 127) << 17) | (unsigned)s;  // s < 2^17
        myloc[i] = atomicAdd(&sm.sc.histL[b], 1);
      } else myb[i] = -1;
    }
    __syncthreads();
    {   // exclusive scan of histL[0..511]
      int v0 = sm.sc.histL[2 * t], v1 = sm.sc.histL[2 * t + 1];
      int pair = v0 + v1, inc = pair;
      #pragma unroll
      for (int off = 1; off < 64; off <<= 1) {
        int nv = __shfl_up(inc, off);
        if (lane >= off) inc += nv;
      }
      if (lane == 63) sm.sc.wsumS[wid] = inc;
      __syncthreads();
      if (t == 0) {
        int run = 0;
        #pragma unroll
        for (int w = 0; w < 4; ++w) { int c = sm.sc.wsumS[w]; sm.sc.wsumS[w] = run; run += c; }
        sm.sc.nvalS = run;
      }
      __syncthreads();
      int excl = sm.sc.wsumS[wid] + inc - pair;
      sm.sc.baseL[2 * t] = excl;
      sm.sc.baseL[2 * t + 1] = excl + v0;
    }
    __syncthreads();
    #pragma unroll
    for (int i = 0; i < CHUNK / 256; ++i)
      if (myb[i] >= 0) {
        int p = sm.sc.baseL[myb[i]] + myloc[i];
        sm.sc.staging[p] = mypay[i];
        sm.sc.bktidL[p] = (unsigned short)myb[i];
      }
    for (int b = t; b < NBUCKET; b += 256) {   // reserve chunks (relative)
      int c = sm.sc.histL[b];
      sm.sc.gbaseL[b] = c ? atomicAdd(&cursor[b], c) : 0;
    }
    __syncthreads();
    const int nval = sm.sc.nvalS;
    for (int j = t; j < nval; j += 256) {
      int b = sm.sc.bktidL[j];
      int off = sm.sc.gbaseL[b] + (j - sm.sc.baseL[b]);
      if (off < BCAP) csr[b * BCAP + off] = sm.sc.staging[j];  // overflow guard
    }
  } else {
    // ---------------- proj1 (MFMA) + fused a1 epilogue ----------------------
    const int pb = blockIdx.x - NSCAT;        // 0..NPROJ1-1
    if (t < 128) ((float*)sm.part)[t] = 0.f;
    __syncthreads();
    const int w = wid;
    const int m = lane & 15, quad = lane >> 4;
    const int row0 = pb * 32;
    const int n0 = w * 32;
    const int head = w >> 1;                  // cols n0.. all in one head
    f32x4 acc[2][2] = {};
    #pragma unroll
    for (int kk = 0; kk < 4; ++kk) {
      bf16x8 afr[2], bfr[2];
      #pragma unroll
      for (int mt = 0; mt < 2; ++mt) {
        int row = row0 + mt * 16 + m;
        if (row >= N_NODES) row = N_NODES - 1;
        afr[mt] = pack_bf8(x + (size_t)row * 128 + kk * 32 + quad * 8);
      }
      #pragma unroll
      for (int nt = 0; nt < 2; ++nt)
        bfr[nt] = *(const bf16x8*)&Wb1g[((((kk << 2) + quad) << 7) + n0 + nt * 16 + m) * 8];
      #pragma unroll
      for (int mt = 0; mt < 2; ++mt)
        #pragma unroll
        for (int nt = 0; nt < 2; ++nt)
          acc[mt][nt] = __builtin_amdgcn_mfma_f32_16x16x32_bf16(
              afr[mt], bfr[nt], acc[mt][nt], 0, 0, 0);
    }
    // per-lane att values for this wave's two 16-col groups (within head)
    float asv[2], adv[2];
    #pragma unroll
    for (int nt = 0; nt < 2; ++nt) {
      int cc = ((n0 & 63) + nt * 16 + m);
      asv[nt] = att_src[head * HID + cc];
      adv[nt] = att_dst[head * HID + cc];
    }
    #pragma unroll
    for (int mt = 0; mt < 2; ++mt)
      #pragma unroll
      for (int r = 0; r < 4; ++r) {
        int row = row0 + mt * 16 + quad * 4 + r;
        if (row < N_NODES) {
          #pragma unroll
          for (int nt = 0; nt < 2; ++nt)
            h1b[(size_t)row * 128 + n0 + nt * 16 + m] = f2bf(acc[mt][nt][r]);
        }
        float s = acc[mt][0][r] * asv[0] + acc[mt][1][r] * asv[1];
        float d = acc[mt][0][r] * adv[0] + acc[mt][1][r] * adv[1];
        #pragma unroll
        for (int off = 8; off; off >>= 1) {   // reduce 16 col-lanes (in-quad)
          s += __shfl_xor(s, off);
          d += __shfl_xor(d, off);
        }
        if (m == 0) {   // two waves per head accumulate
          atomicAdd(&sm.part[mt * 16 + quad * 4 + r][head], s);
          atomicAdd(&sm.part[mt * 16 + quad * 4 + r][2 + head], d);
        }
      }
    __syncthreads();
    if (t < 32) {
      int row = row0 + t;
      if (row < N_NODES)
        *(float4*)&a1[(size_t)row * 4] = make_float4(
            sm.part[t][0], sm.part[t][1], sm.part[t][2], sm.part[t][3]);
    }
  }
}

// Phase 2: one block per bucket; per-node histogram + prefix + in-place
// re-scatter within an L2-local 12 KB window.
__global__ __launch_bounds__(256) void bucket_fill_kernel(
    const int* __restrict__ cursor, unsigned* __restrict__ csr,
    int* __restrict__ counts, int* __restrict__ cend) {
  __shared__ unsigned eseg[BCAP];
  __shared__ int hist[128];
  __shared__ int basef[128];
  __shared__ int cur[128];
  const int b = blockIdx.x, t = threadIdx.x;
  const int segbase = b * BCAP;
  int cnt = cursor[b];
  if (cnt > BCAP) cnt = BCAP;
  if (t < 128) hist[t] = 0;
  __syncthreads();
  for (int j = t; j < cnt; j += 256) {
    unsigned u = csr[segbase + j];
    eseg[j] = u;
    atomicAdd(&hist[u >> 17], 1);
  }
  __syncthreads();
  if (t < 64) {   // exclusive scan of hist[0..127]
    int v0 = hist[2 * t], v1 = hist[2 * t + 1];
    int pair = v0 + v1, inc = pair;
    #pragma unroll
    for (int off = 1; off < 64; off <<= 1) {
      int nv = __shfl_up(inc, off);
      if (t >= off) inc += nv;
    }
    int excl = inc - pair;
    basef[2 * t] = excl;
    basef[2 * t + 1] = excl + v0;
  }
  __syncthreads();
  if (t < 128) {
    cur[t] = basef[t];
    int n = b * 128 + t;
    if (n < N_NODES) {
      counts[n] = hist[t];
      cend[n] = segbase + basef[t] + hist[t];
    }
  }
  __syncthreads();
  for (int j = t; j < cnt; j += 256) {
    unsigned u = eseg[j];
    int dl = u >> 17;
    int p = atomicAdd(&cur[dl], 1);
    csr[segbase + p] = u & 0x1FFFF;    // src id only
  }
}

// ==== fused layer-1 aggregate + proj2 + a2 ==================================
// 4 nodes/block, 1 node/wave (round-1 grid granularity: 12500 blocks vs 2048
// resident -> 6.1x oversubscription, small drain tail). The wave's node row
// is staged in LDS (bf16, stride 136 elems = conflict-managed), then each
// wave does a 16x16x32 MFMA where only A-rows 0..3 are valid: C row r
// depends only on A row r, so garbage rows 4..15 are simply discarded.
__global__ __launch_bounds__(256) void agg1_proj2_kernel(
    const int* __restrict__ counts, const int* __restrict__ cend,
    const unsigned* __restrict__ csr_src, const float4* __restrict__ a1,
    const unsigned* __restrict__ h1b2, const float* __restrict__ b,
    const unsigned short* __restrict__ Wb2g,
    const float* __restrict__ asmu, const float* __restrict__ admu,
    const float* __restrict__ aslv, const float* __restrict__ adlv,
    unsigned short* __restrict__ h2b, float* __restrict__ a2) {
  __shared__ __align__(16) float2 w_lds[4][MAXDEG1];           // 3 KB
  __shared__ __align__(16) unsigned short s_lds[4][MAXDEG1];   // 0.75 KB
  __shared__ __align__(16) unsigned short hrow[16][136];       // 4.25 KB (rows 0-3 used)
  __shared__ __align__(16) float sm_a2[4][4];
  const int t = threadIdx.x, wid = t >> 6, lane = t & 63;
  if (t < 16) ((float*)sm_a2)[t] = 0.f;
  const int nbase = blockIdx.x * 4;
  const int n = nbase + wid;                 // this wave's node

  // ---- phase 1: per-edge softmax weights into LDS + denominators ----------
  const int end = cend[n];
  int cnt = counts[n]; if (cnt > MAXDEG1) cnt = MAXDEG1;
  const int beg = end - cnt;
  const float4 bv = a1[n];
  float p0 = 0.f, p1 = 0.f;
  for (int i = lane; i < cnt; i += 64) {
    int s = (int)csr_src[beg + i];
    float4 av = a1[s];
    float l0 = av.x + bv.z; l0 = l0 > 0.f ? l0 : NEG_SLOPE * l0;
    float l1 = av.y + bv.w; l1 = l1 > 0.f ? l1 : NEG_SLOPE * l1;
    float e0 = expf(l0), e1 = expf(l1);
    w_lds[wid][i] = make_float2(e0, e1);
    s_lds[wid][i] = (unsigned short)s;        // src < 50000 < 2^16
    p0 += e0; p1 += e1;
  }
  #pragma unroll
  for (int off = 32; off; off >>= 1) {
    p0 += __shfl_xor(p0, off);
    p1 += __shfl_xor(p1, off);
  }

  // ---- phase 2: wide gather. lane = 16*g + lq; 4 edges per iteration ------
  const int g = lane >> 4, lq = lane & 15, head = lq >> 3;
  {
    float acc[8] = {0.f, 0.f, 0.f, 0.f, 0.f, 0.f, 0.f, 0.f};
    #pragma unroll 2
    for (int i = g; i < cnt; i += 4) {
      int s = (int)s_lds[wid][i];
      float w = ((const float*)&w_lds[wid][i])[head];
      uint4 u = *(const uint4*)(h1b2 + (size_t)s * 64 + lq * 4);
      acc[0] += bf_lo(u.x) * w; acc[1] += bf_hi(u.x) * w;
      acc[2] += bf_lo(u.y) * w; acc[3] += bf_hi(u.y) * w;
      acc[4] += bf_lo(u.z) * w; acc[5] += bf_hi(u.z) * w;
      acc[6] += bf_lo(u.w) * w; acc[7] += bf_hi(u.w) * w;
    }
    #pragma unroll
    for (int jj = 0; jj < 8; ++jj) {          // fold the 4 edge groups
      acc[jj] += __shfl_xor(acc[jj], 16);
      acc[jj] += __shfl_xor(acc[jj], 32);
    }
    if (g == 0) {
      float inv = 1.f / ((head ? p1 : p0) + 1e-16f);
      bf16x8 o;
      #pragma unroll
      for (int jj = 0; jj < 8; ++jj) {
        float v = acc[jj] * inv + b[lq * 8 + jj];
        v = v > 0.f ? v : (expf(v) - 1.f);     // ELU fused
        o[jj] = (short)f2bf(v);
      }
      *(bf16x8*)&hrow[wid][lq * 8] = o;        // 16B store, bank-even
    }
  }
  __syncthreads();

  // ---- fused proj2: 4x128 (LDS bf16, rows 0-3) @ 128x64 -> h2b + a2 -------
  const int m = lane & 15, quad = lane >> 4;
  const int c = wid * 16 + m;          // output channel 0..63 (mu: 0-31, lv: 32-63)
  const int j = wid >> 1;              // 0 = mu, 1 = lv
  f32x4 acc2 = {};
  #pragma unroll
  for (int kk = 0; kk < 4; ++kk) {
    bf16x8 af = *(const bf16x8*)&hrow[m][kk * 32 + quad * 8];  // rows >=4: garbage, discarded
    bf16x8 bf = *(const bf16x8*)&Wb2g[((((kk << 2) + quad) << 6) + c) * 8];
    acc2 = __builtin_amdgcn_mfma_f32_16x16x32_bf16(af, bf, acc2, 0, 0, 0);
  }
  const float asv = (j ? aslv : asmu)[(wid & 1) * 16 + m];
  const float adv = (j ? adlv : admu)[(wid & 1) * 16 + m];
  #pragma unroll
  for (int r = 0; r < 4; ++r) {
    // C row = quad*4 + r; only quad==0 holds the 4 valid node rows
    float s = acc2[r] * asv, d = acc2[r] * adv;
    #pragma unroll
    for (int off = 8; off; off >>= 1) {   // reduce the 16 col-lanes (in-quad)
      s += __shfl_xor(s, off);
      d += __shfl_xor(d, off);
    }
    if (quad == 0) {
      h2b[(size_t)(nbase + r) * 64 + c] = f2bf(acc2[r]);
      if (m == 0) {
        atomicAdd(&sm_a2[r][j * 2 + 0], s);
        atomicAdd(&sm_a2[r][j * 2 + 1], d);
      }
    }
  }
  __syncthreads();
  if (t < 4)
    *(float4*)&a2[(size_t)(nbase + t) * 4] = make_float4(
        sm_a2[t][0], sm_a2[t][1], sm_a2[t][2], sm_a2[t][3]);
}

// ---- layer-2 gather-aggregate: 4 nodes/block (one wave each) ---------------
// 8 lanes per edge (8 bf16 channels each, 16B dwordx4), 8 edges per
// wave-iteration.
__global__ __launch_bounds__(256) void agg2_csr_kernel(
    const int* __restrict__ counts, const int* __restrict__ cend,
    const unsigned* __restrict__ csr_src, const float4* __restrict__ a2,
    const unsigned* __restrict__ h2b2,
    const float* __restrict__ bmu, const float* __restrict__ blv,
    float* __restrict__ out) {
  __shared__ float2 w_lds[4][MAXDEG];
  __shared__ int   s_lds[4][MAXDEG];
  const int t = threadIdx.x, wid = t >> 6, lane = t & 63;
  const int n = blockIdx.x * 4 + wid;        // grid = N/4 exactly
  const int end = cend[n];
  int cnt = counts[n];
  if (cnt > MAXDEG) cnt = MAXDEG;
  const int beg = end - cnt;
  const float4 bv = a2[n];
  // ---- phase 1: per-edge softmax weights (mu, lv) + denominators ----
  float p0 = 0.f, p1 = 0.f;
  for (int i = lane; i < cnt; i += 64) {
    int s = (int)csr_src[beg + i];
    float4 av = a2[s];
    float l0 = av.x + bv.y; l0 = l0 > 0.f ? l0 : NEG_SLOPE * l0;  // mu
    float l1 = av.z + bv.w; l1 = l1 > 0.f ? l1 : NEG_SLOPE * l1;  // lv
    float e0 = expf(l0), e1 = expf(l1);
    w_lds[wid][i] = make_float2(e0, e1);
    s_lds[wid][i] = s;
    p0 += e0; p1 += e1;
  }
  #pragma unroll
  for (int off = 32; off; off >>= 1) {
    p0 += __shfl_xor(p0, off);
    p1 += __shfl_xor(p1, off);
  }
  __syncthreads();
  // ---- phase 2: wide gather. lane = 8*g + lq; edge group g in [0,8) ----
  const int g = lane >> 3;
  const int lq = lane & 7;                   // channel octet: ch lq*8..lq*8+7
  const int j = lq >> 2;                     // 0 = mu (ch<32), 1 = lv
  float acc[8] = {0.f, 0.f, 0.f, 0.f, 0.f, 0.f, 0.f, 0.f};
  #pragma unroll 2
  for (int i = g; i < cnt; i += 8) {
    int s = s_lds[wid][i];
    float w = ((const float*)&w_lds[wid][i])[j];
    uint4 u = *(const uint4*)(h2b2 + (size_t)s * 32 + lq * 4);
    acc[0] += bf_lo(u.x) * w; acc[1] += bf_hi(u.x) * w;
    acc[2] += bf_lo(u.y) * w; acc[3] += bf_hi(u.y) * w;
    acc[4] += bf_lo(u.z) * w; acc[5] += bf_hi(u.z) * w;
    acc[6] += bf_lo(u.w) * w; acc[7] += bf_hi(u.w) * w;
  }
  #pragma unroll
  for (int jj = 0; jj < 8; ++jj) {           // fold the 8 edge groups
    acc[jj] += __shfl_xor(acc[jj], 8);
    acc[jj] += __shfl_xor(acc[jj], 16);
    acc[jj] += __shfl_xor(acc[jj], 32);
  }
  if (g == 0) {
    float inv = 1.f / ((j ? p1 : p0) + 1e-16f);
    const float* bb = j ? blv : bmu;
    const int o = (lq & 3) * 8;              // channel within the 32-latent
    float r[8];
    #pragma unroll
    for (int jj = 0; jj < 8; ++jj) r[jj] = acc[jj] * inv + bb[o + jj];
    float4* dst = (float4*)(out + (size_t)j * N_NODES * LAT + (size_t)n * LAT + o);
    dst[0] = make_float4(r[0], r[1], r[2], r[3]);
    dst[1] = make_float4(r[4], r[5], r[6], r[7]);
  }
}

extern "C" void kernel_launch(void* const* d_in, const int* in_sizes, int n_in,
                              void* d_out, int out_size, void* d_ws, size_t ws_size,
                              hipStream_t stream) {
  const float* x        = (const float*)d_in[0];
  const int* ei         = (const int*)d_in[1];   // int32 per harness contract
  const float* W1       = (const float*)d_in[2];
  const float* att_src1 = (const float*)d_in[3];
  const float* att_dst1 = (const float*)d_in[4];
  const float* b1       = (const float*)d_in[5];
  const float* Wmu      = (const float*)d_in[6];
  const float* asmu     = (const float*)d_in[7];
  const float* admu     = (const float*)d_in[8];
  const float* bmu      = (const float*)d_in[9];
  const float* Wlv      = (const float*)d_in[10];
  const float* aslv     = (const float*)d_in[11];
  const float* adlv     = (const float*)d_in[12];
  const float* blv      = (const float*)d_in[13];
  float* out = (float*)d_out;

  // workspace layout (4-B units) — all 16-B-vector-loaded buffers 16-B aligned:
  //  [hact N*128 (dead slot, kept for layout stability) | a1 N*4 | a2 N*4 |
  //   h1b N*64(bf16 pairs) | h2b N*32 | Wb1g 4096 | Wb2g 2048 |
  //   counts N | cend N | cursor NBUCKET | csr N_B*BCAP]
  float* ws   = (float*)d_ws;
  float* hact = ws;                          // dead slot (proj2 fused away)
  float* a1   = hact + (size_t)N_NODES * 128;
  float* a2   = a1 + (size_t)N_NODES * 4;
  unsigned short* h1b = (unsigned short*)(a2 + (size_t)N_NODES * 4);
  unsigned short* h2b = h1b + (size_t)N_NODES * 128;
  unsigned short* Wb1g = h2b + (size_t)N_NODES * 64;   // byte off 46,400,000 (16-aligned)
  unsigned short* Wb2g = Wb1g + 16384;                  // +32 KB (16-aligned)
  int* counts = (int*)(Wb2g + 8192);
  int* cend   = counts + N_NODES;
  int* cursor = cend + N_NODES;
  unsigned* csr = (unsigned*)(cursor + NBUCKET);

  // prep: zero cursors + pack both weight matrices into B-frag layout
  prep_kernel<<<97, 256, 0, stream>>>(W1, Wmu, Wlv, cursor, Wb1g, Wb2g);

  // K1: bucket_scatter (416 blocks) || proj1+a1 (1563 blocks)
  k1_kernel<<<NSCAT + NPROJ1, 256, 0, stream>>>(
      ei, cursor, csr, x, Wb1g, att_src1, att_dst1, h1b, a1);
  bucket_fill_kernel<<<NBUCKET, 256, 0, stream>>>(cursor, csr, counts, cend);
  // fused: layer-1 aggregate + ELU + proj2 + a2 (hact stays in LDS)
  agg1_proj2_kernel<<<N_NODES / 4, 256, 0, stream>>>(
      counts, cend, csr, (const float4*)a1, (const unsigned*)h1b, b1,
      Wb2g, asmu, admu, aslv, adlv, h2b, a2);
  agg2_csr_kernel<<<N_NODES / 4, 256, 0, stream>>>(
      counts, cend, csr, (const float4*)a2, (const unsigned*)h2b, bmu, blv, out);
}

// Round 5
// 203.506 us; speedup vs baseline: 1.0663x; 1.0663x over previous
//
#include <hip/hip_runtime.h>
#include <hip/hip_bf16.h>

#define N_NODES 50000
#define N_EDGES 800000
#define EP (N_EDGES + N_NODES)   // with self-loops
#define IN_C 128
#define HID 64
#define HEADS 2
#define LAT 32
#define NEG_SLOPE 0.2f
#define MAXDEG 256     // max in-degree for agg2 LDS; deg = 1 + Poisson(16)
#define MAXDEG1 96     // agg1 fused kernel: P(Poisson(16) > 95) ~ e^-90
#define NBUCKET 391    // ceil(N_NODES/128): coarse dst-buckets of 128 nodes
#define BCAP 3072      // bucket capacity; expect ~2176 +- 47 (20 sigma margin)
#define CHUNK 2048     // edges per scatter block (18KB LDS -> 8 blocks/CU)
#define NSCAT ((EP + CHUNK - 1) / CHUNK)   // 416 scatter blocks
#define NPROJ1 ((N_NODES + 31) / 32)       // 1563 proj1 blocks

typedef __attribute__((ext_vector_type(8))) short bf16x8;
typedef __attribute__((ext_vector_type(4))) float f32x4;

// fp32 -> bf16 round-to-nearest-even
__device__ __forceinline__ unsigned short f2bf(float f) {
  unsigned u = __float_as_uint(f);
  u += 0x7FFF + ((u >> 16) & 1);
  return (unsigned short)(u >> 16);
}
__device__ __forceinline__ float bf_lo(unsigned u) { return __uint_as_float(u << 16); }
__device__ __forceinline__ float bf_hi(unsigned u) { return __uint_as_float(u & 0xFFFF0000u); }

__device__ __forceinline__ bf16x8 pack_bf8(const float* __restrict__ p) {
  float4 a = *(const float4*)p;
  float4 b = *(const float4*)(p + 4);
  bf16x8 r;
  r[0] = (short)f2bf(a.x); r[1] = (short)f2bf(a.y);
  r[2] = (short)f2bf(a.z); r[3] = (short)f2bf(a.w);
  r[4] = (short)f2bf(b.x); r[5] = (short)f2bf(b.y);
  r[6] = (short)f2bf(b.z); r[7] = (short)f2bf(b.w);
  return r;
}

// ======= prep: zero cursors + pack W1/[Wmu|Wlv] into B-fragment layout ======
// Wb layout: [(kk*4+quad)*N + n]*8 + j  holds  W[k = kk*32+quad*8+j][n]
__global__ __launch_bounds__(256) void prep_kernel(
    const float* __restrict__ W1, const float* __restrict__ Wmu,
    const float* __restrict__ Wlv, int* __restrict__ cursor,
    unsigned short* __restrict__ Wb1g, unsigned short* __restrict__ Wb2g) {
  const int b = blockIdx.x, t = threadIdx.x;
  if (b == 0) {
    for (int i = t; i < NBUCKET; i += 256) cursor[i] = 0;
  } else if (b <= 64) {
    int i = (b - 1) * 256 + t;       // [0, 16384)
    int k = i >> 7, n = i & 127;
    int kk = k >> 5, q = (k >> 3) & 3, j = k & 7;
    Wb1g[((((kk << 2) + q) << 7) + n) * 8 + j] = f2bf(W1[i]);
  } else {
    int i = (b - 65) * 256 + t;      // [0, 8192)
    int k = i >> 6, n = i & 63;
    float v = (n < 32) ? Wmu[k * 32 + n] : Wlv[k * 32 + (n - 32)];
    int kk = k >> 5, q = (k >> 3) & 3, j = k & 7;
    Wb2g[((((kk << 2) + q) << 6) + n) * 8 + j] = f2bf(v);
  }
}

// ---------------- K1 shared-memory overlay (scatter | proj1) ----------------
struct ScatSmem {
  int histL[512];
  int baseL[512];
  int gbaseL[512];
  int wsumS[4];
  int nvalS;
  unsigned staging[CHUNK];
  unsigned short bktidL[CHUNK];
};
struct Proj1Smem {
  float part[32][4];
  unsigned short xs[32][136];   // bf16 x-tile, stride 136 (272 B, conflict-managed)
};
union K1Smem { ScatSmem sc; Proj1Smem p1; };

// ================= K1: bucket_scatter (blocks 0..NSCAT) =====================
// =================     proj1 (MFMA, LDS-staged A, global B-frags) + a1 ======
__global__ __launch_bounds__(256) void k1_kernel(
    const int* __restrict__ ei, int* __restrict__ cursor,
    unsigned* __restrict__ csr,
    const float* __restrict__ x, const unsigned short* __restrict__ Wb1g,
    const float* __restrict__ att_src, const float* __restrict__ att_dst,
    unsigned short* __restrict__ h1b, float* __restrict__ a1) {
  __shared__ K1Smem sm;
  const int t = threadIdx.x, lane = t & 63, wid = t >> 6;

  if (blockIdx.x < NSCAT) {
    // ---------------- bucket scatter: LDS binning, chunked global writes ----
    for (int i = t; i < 512; i += 256) sm.sc.histL[i] = 0;
    __syncthreads();
    int myb[CHUNK / 256];
    int myloc[CHUNK / 256];
    unsigned mypay[CHUNK / 256];
    #pragma unroll
    for (int i = 0; i < CHUNK / 256; ++i) {
      int e = blockIdx.x * CHUNK + i * 256 + t;
      if (e < EP) {
        int s, d;
        if (e < N_EDGES) { s = ei[e]; d = ei[N_EDGES + e]; }
        else { s = d = e - N_EDGES; }
        int b = d >> 7;
        myb[i] = b;
        mypay[i] = ((unsigned)(d & 127) << 17) | (unsigned)s;  // s < 2^17
        myloc[i] = atomicAdd(&sm.sc.histL[b], 1);
      } else myb[i] = -1;
    }
    __syncthreads();
    {   // exclusive scan of histL[0..511]
      int v0 = sm.sc.histL[2 * t], v1 = sm.sc.histL[2 * t + 1];
      int pair = v0 + v1, inc = pair;
      #pragma unroll
      for (int off = 1; off < 64; off <<= 1) {
        int nv = __shfl_up(inc, off);
        if (lane >= off) inc += nv;
      }
      if (lane == 63) sm.sc.wsumS[wid] = inc;
      __syncthreads();
      if (t == 0) {
        int run = 0;
        #pragma unroll
        for (int w = 0; w < 4; ++w) { int c = sm.sc.wsumS[w]; sm.sc.wsumS[w] = run; run += c; }
        sm.sc.nvalS = run;
      }
      __syncthreads();
      int excl = sm.sc.wsumS[wid] + inc - pair;
      sm.sc.baseL[2 * t] = excl;
      sm.sc.baseL[2 * t + 1] = excl + v0;
    }
    __syncthreads();
    #pragma unroll
    for (int i = 0; i < CHUNK / 256; ++i)
      if (myb[i] >= 0) {
        int p = sm.sc.baseL[myb[i]] + myloc[i];
        sm.sc.staging[p] = mypay[i];
        sm.sc.bktidL[p] = (unsigned short)myb[i];
      }
    for (int b = t; b < NBUCKET; b += 256) {   // reserve chunks (relative)
      int c = sm.sc.histL[b];
      sm.sc.gbaseL[b] = c ? atomicAdd(&cursor[b], c) : 0;
    }
    __syncthreads();
    const int nval = sm.sc.nvalS;
    for (int j = t; j < nval; j += 256) {
      int b = sm.sc.bktidL[j];
      int off = sm.sc.gbaseL[b] + (j - sm.sc.baseL[b]);
      if (off < BCAP) csr[b * BCAP + off] = sm.sc.staging[j];  // overflow guard
    }
  } else {
    // ---------------- proj1 (MFMA) + fused a1 epilogue ----------------------
    const int pb = blockIdx.x - NSCAT;        // 0..NPROJ1-1
    const int row0 = pb * 32;
    if (t < 128) ((float*)sm.p1.part)[t] = 0.f;
    // stage the 32x128 x-tile as bf16 ONCE (was: 4 waves each re-converting)
    {
      int row = t >> 3;                  // 0..31
      int col0 = (t & 7) * 16;           // 0,16,...,112
      int gr = row0 + row; if (gr >= N_NODES) gr = N_NODES - 1;
      const float* xp = x + (size_t)gr * 128 + col0;
      *(bf16x8*)&sm.p1.xs[row][col0]     = pack_bf8(xp);
      *(bf16x8*)&sm.p1.xs[row][col0 + 8] = pack_bf8(xp + 8);
    }
    __syncthreads();
    const int w = wid;
    const int m = lane & 15, quad = lane >> 4;
    const int n0 = w * 32;
    const int head = w >> 1;                  // cols n0.. all in one head
    f32x4 acc[2][2] = {};
    #pragma unroll
    for (int kk = 0; kk < 4; ++kk) {
      bf16x8 afr[2], bfr[2];
      #pragma unroll
      for (int mt = 0; mt < 2; ++mt)
        afr[mt] = *(const bf16x8*)&sm.p1.xs[mt * 16 + m][kk * 32 + quad * 8];
      #pragma unroll
      for (int nt = 0; nt < 2; ++nt)
        bfr[nt] = *(const bf16x8*)&Wb1g[((((kk << 2) + quad) << 7) + n0 + nt * 16 + m) * 8];
      #pragma unroll
      for (int mt = 0; mt < 2; ++mt)
        #pragma unroll
        for (int nt = 0; nt < 2; ++nt)
          acc[mt][nt] = __builtin_amdgcn_mfma_f32_16x16x32_bf16(
              afr[mt], bfr[nt], acc[mt][nt], 0, 0, 0);
    }
    // per-lane att values for this wave's two 16-col groups (within head)
    float asv[2], adv[2];
    #pragma unroll
    for (int nt = 0; nt < 2; ++nt) {
      int cc = ((n0 & 63) + nt * 16 + m);
      asv[nt] = att_src[head * HID + cc];
      adv[nt] = att_dst[head * HID + cc];
    }
    #pragma unroll
    for (int mt = 0; mt < 2; ++mt)
      #pragma unroll
      for (int r = 0; r < 4; ++r) {
        int row = row0 + mt * 16 + quad * 4 + r;
        if (row < N_NODES) {
          #pragma unroll
          for (int nt = 0; nt < 2; ++nt)
            h1b[(size_t)row * 128 + n0 + nt * 16 + m] = f2bf(acc[mt][nt][r]);
        }
        float s = acc[mt][0][r] * asv[0] + acc[mt][1][r] * asv[1];
        float d = acc[mt][0][r] * adv[0] + acc[mt][1][r] * adv[1];
        #pragma unroll
        for (int off = 8; off; off >>= 1) {   // reduce 16 col-lanes (in-quad)
          s += __shfl_xor(s, off);
          d += __shfl_xor(d, off);
        }
        if (m == 0) {   // two waves per head accumulate
          atomicAdd(&sm.p1.part[mt * 16 + quad * 4 + r][head], s);
          atomicAdd(&sm.p1.part[mt * 16 + quad * 4 + r][2 + head], d);
        }
      }
    __syncthreads();
    if (t < 32) {
      int row = row0 + t;
      if (row < N_NODES)
        *(float4*)&a1[(size_t)row * 4] = make_float4(
            sm.p1.part[t][0], sm.p1.part[t][1], sm.p1.part[t][2], sm.p1.part[t][3]);
    }
  }
}

// Phase 2: one block per bucket; per-node histogram + prefix + in-place
// re-scatter within an L2-local 12 KB window.
__global__ __launch_bounds__(256) void bucket_fill_kernel(
    const int* __restrict__ cursor, unsigned* __restrict__ csr,
    int* __restrict__ counts, int* __restrict__ cend) {
  __shared__ unsigned eseg[BCAP];
  __shared__ int hist[128];
  __shared__ int basef[128];
  __shared__ int cur[128];
  const int b = blockIdx.x, t = threadIdx.x;
  const int segbase = b * BCAP;
  int cnt = cursor[b];
  if (cnt > BCAP) cnt = BCAP;
  if (t < 128) hist[t] = 0;
  __syncthreads();
  for (int j = t; j < cnt; j += 256) {
    unsigned u = csr[segbase + j];
    eseg[j] = u;
    atomicAdd(&hist[u >> 17], 1);
  }
  __syncthreads();
  if (t < 64) {   // exclusive scan of hist[0..127]
    int v0 = hist[2 * t], v1 = hist[2 * t + 1];
    int pair = v0 + v1, inc = pair;
    #pragma unroll
    for (int off = 1; off < 64; off <<= 1) {
      int nv = __shfl_up(inc, off);
      if (t >= off) inc += nv;
    }
    int excl = inc - pair;
    basef[2 * t] = excl;
    basef[2 * t + 1] = excl + v0;
  }
  __syncthreads();
  if (t < 128) {
    cur[t] = basef[t];
    int n = b * 128 + t;
    if (n < N_NODES) {
      counts[n] = hist[t];
      cend[n] = segbase + basef[t] + hist[t];
    }
  }
  __syncthreads();
  for (int j = t; j < cnt; j += 256) {
    unsigned u = eseg[j];
    int dl = u >> 17;
    int p = atomicAdd(&cur[dl], 1);
    csr[segbase + p] = u & 0x1FFFF;    // src id only
  }
}

// ==== fused layer-1 aggregate + proj2 + a2 (round-3 proven structure) =======
// 16 nodes/block (4 waves x 4 nodes). Aggregated rows staged in LDS as bf16
// with row stride 136 elems (272 B): conflict-managed ds_read_b128 for the
// MFMA A-fragments, consumed directly without f32->bf16 repack.
__global__ __launch_bounds__(256) void agg1_proj2_kernel(
    const int* __restrict__ counts, const int* __restrict__ cend,
    const unsigned* __restrict__ csr_src, const float4* __restrict__ a1,
    const unsigned* __restrict__ h1b2, const float* __restrict__ b,
    const unsigned short* __restrict__ Wb2g,
    const float* __restrict__ asmu, const float* __restrict__ admu,
    const float* __restrict__ aslv, const float* __restrict__ adlv,
    unsigned short* __restrict__ h2b, float* __restrict__ a2) {
  __shared__ __align__(16) float2 w_lds[16][MAXDEG1];          // 12 KB
  __shared__ __align__(16) unsigned short s_lds[16][MAXDEG1];  // 3 KB
  __shared__ __align__(16) unsigned short hrow[16][136];       // 4.25 KB, bf16
  __shared__ __align__(16) float sm_a2[16][4];
  const int t = threadIdx.x, wid = t >> 6, lane = t & 63;
  if (t < 64) ((float*)sm_a2)[t] = 0.f;
  const int nbase = blockIdx.x * 16;

  // ---- phase 1: per-edge softmax weights into LDS + denominators ----------
  int cnt_r[4];
  float p0r[4], p1r[4];
  #pragma unroll
  for (int nd = 0; nd < 4; ++nd) {
    const int slot = wid * 4 + nd;
    const int n = nbase + slot;
    const int end = cend[n];
    int cnt = counts[n]; if (cnt > MAXDEG1) cnt = MAXDEG1;
    const int beg = end - cnt;
    cnt_r[nd] = cnt;
    const float4 bv = a1[n];
    float p0 = 0.f, p1 = 0.f;
    for (int i = lane; i < cnt; i += 64) {
      int s = (int)csr_src[beg + i];
      float4 av = a1[s];
      float l0 = av.x + bv.z; l0 = l0 > 0.f ? l0 : NEG_SLOPE * l0;
      float l1 = av.y + bv.w; l1 = l1 > 0.f ? l1 : NEG_SLOPE * l1;
      float e0 = expf(l0), e1 = expf(l1);
      w_lds[slot][i] = make_float2(e0, e1);
      s_lds[slot][i] = (unsigned short)s;      // src < 50000 < 2^16
      p0 += e0; p1 += e1;
    }
    #pragma unroll
    for (int off = 32; off; off >>= 1) {
      p0 += __shfl_xor(p0, off);
      p1 += __shfl_xor(p1, off);
    }
    p0r[nd] = p0; p1r[nd] = p1;
  }
  // no barrier needed: all slots are wave-private

  // ---- phase 2: wide gather. lane = 16*g + lq; 4 edges per iteration ------
  const int g = lane >> 4, lq = lane & 15, head = lq >> 3;
  #pragma unroll
  for (int nd = 0; nd < 4; ++nd) {
    const int slot = wid * 4 + nd;
    const int cnt = cnt_r[nd];
    float acc[8] = {0.f, 0.f, 0.f, 0.f, 0.f, 0.f, 0.f, 0.f};
    #pragma unroll 2
    for (int i = g; i < cnt; i += 4) {
      int s = (int)s_lds[slot][i];
      float w = ((const float*)&w_lds[slot][i])[head];
      uint4 u = *(const uint4*)(h1b2 + (size_t)s * 64 + lq * 4);
      acc[0] += bf_lo(u.x) * w; acc[1] += bf_hi(u.x) * w;
      acc[2] += bf_lo(u.y) * w; acc[3] += bf_hi(u.y) * w;
      acc[4] += bf_lo(u.z) * w; acc[5] += bf_hi(u.z) * w;
      acc[6] += bf_lo(u.w) * w; acc[7] += bf_hi(u.w) * w;
    }
    #pragma unroll
    for (int jj = 0; jj < 8; ++jj) {          // fold the 4 edge groups
      acc[jj] += __shfl_xor(acc[jj], 16);
      acc[jj] += __shfl_xor(acc[jj], 32);
    }
    if (g == 0) {
      float inv = 1.f / ((head ? p1r[nd] : p0r[nd]) + 1e-16f);
      bf16x8 o;
      #pragma unroll
      for (int jj = 0; jj < 8; ++jj) {
        float v = acc[jj] * inv + b[lq * 8 + jj];
        v = v > 0.f ? v : (expf(v) - 1.f);     // ELU fused
        o[jj] = (short)f2bf(v);
      }
      *(bf16x8*)&hrow[slot][lq * 8] = o;       // 16B store, bank-even
    }
  }
  __syncthreads();

  // ---- fused proj2: 16x128 (LDS bf16) @ 128x64 (Wb2g frags) -> h2b + a2 ---
  const int m = lane & 15, quad = lane >> 4;
  const int c = wid * 16 + m;          // output channel 0..63 (mu: 0-31, lv: 32-63)
  const int j = wid >> 1;              // 0 = mu, 1 = lv
  f32x4 acc2 = {};
  #pragma unroll
  for (int kk = 0; kk < 4; ++kk) {
    bf16x8 af = *(const bf16x8*)&hrow[m][kk * 32 + quad * 8];
    bf16x8 bf = *(const bf16x8*)&Wb2g[((((kk << 2) + quad) << 6) + c) * 8];
    acc2 = __builtin_amdgcn_mfma_f32_16x16x32_bf16(af, bf, acc2, 0, 0, 0);
  }
  const float asv = (j ? aslv : asmu)[(wid & 1) * 16 + m];
  const float adv = (j ? adlv : admu)[(wid & 1) * 16 + m];
  #pragma unroll
  for (int r = 0; r < 4; ++r) {
    const int slot = quad * 4 + r;     // node row of the C tile
    h2b[(size_t)(nbase + slot) * 64 + c] = f2bf(acc2[r]);
    float s = acc2[r] * asv, d = acc2[r] * adv;
    #pragma unroll
    for (int off = 8; off; off >>= 1) {   // reduce the 16 col-lanes (in-quad)
      s += __shfl_xor(s, off);
      d += __shfl_xor(d, off);
    }
    if (m == 0) {
      atomicAdd(&sm_a2[slot][j * 2 + 0], s);
      atomicAdd(&sm_a2[slot][j * 2 + 1], d);
    }
  }
  __syncthreads();
  if (t < 16)
    *(float4*)&a2[(size_t)(nbase + t) * 4] = make_float4(
        sm_a2[t][0], sm_a2[t][1], sm_a2[t][2], sm_a2[t][3]);
}

// ---- layer-2 gather-aggregate: 4 nodes/block (one wave each) ---------------
// 8 lanes per edge (8 bf16 channels each, 16B dwordx4), 8 edges per
// wave-iteration.
__global__ __launch_bounds__(256) void agg2_csr_kernel(
    const int* __restrict__ counts, const int* __restrict__ cend,
    const unsigned* __restrict__ csr_src, const float4* __restrict__ a2,
    const unsigned* __restrict__ h2b2,
    const float* __restrict__ bmu, const float* __restrict__ blv,
    float* __restrict__ out) {
  __shared__ float2 w_lds[4][MAXDEG];
  __shared__ int   s_lds[4][MAXDEG];
  const int t = threadIdx.x, wid = t >> 6, lane = t & 63;
  const int n = blockIdx.x * 4 + wid;        // grid = N/4 exactly
  const int end = cend[n];
  int cnt = counts[n];
  if (cnt > MAXDEG) cnt = MAXDEG;
  const int beg = end - cnt;
  const float4 bv = a2[n];
  // ---- phase 1: per-edge softmax weights (mu, lv) + denominators ----
  float p0 = 0.f, p1 = 0.f;
  for (int i = lane; i < cnt; i += 64) {
    int s = (int)csr_src[beg + i];
    float4 av = a2[s];
    float l0 = av.x + bv.y; l0 = l0 > 0.f ? l0 : NEG_SLOPE * l0;  // mu
    float l1 = av.z + bv.w; l1 = l1 > 0.f ? l1 : NEG_SLOPE * l1;  // lv
    float e0 = expf(l0), e1 = expf(l1);
    w_lds[wid][i] = make_float2(e0, e1);
    s_lds[wid][i] = s;
    p0 += e0; p1 += e1;
  }
  #pragma unroll
  for (int off = 32; off; off >>= 1) {
    p0 += __shfl_xor(p0, off);
    p1 += __shfl_xor(p1, off);
  }
  __syncthreads();
  // ---- phase 2: wide gather. lane = 8*g + lq; edge group g in [0,8) ----
  const int g = lane >> 3;
  const int lq = lane & 7;                   // channel octet: ch lq*8..lq*8+7
  const int j = lq >> 2;                     // 0 = mu (ch<32), 1 = lv
  float acc[8] = {0.f, 0.f, 0.f, 0.f, 0.f, 0.f, 0.f, 0.f};
  #pragma unroll 2
  for (int i = g; i < cnt; i += 8) {
    int s = s_lds[wid][i];
    float w = ((const float*)&w_lds[wid][i])[j];
    uint4 u = *(const uint4*)(h2b2 + (size_t)s * 32 + lq * 4);
    acc[0] += bf_lo(u.x) * w; acc[1] += bf_hi(u.x) * w;
    acc[2] += bf_lo(u.y) * w; acc[3] += bf_hi(u.y) * w;
    acc[4] += bf_lo(u.z) * w; acc[5] += bf_hi(u.z) * w;
    acc[6] += bf_lo(u.w) * w; acc[7] += bf_hi(u.w) * w;
  }
  #pragma unroll
  for (int jj = 0; jj < 8; ++jj) {           // fold the 8 edge groups
    acc[jj] += __shfl_xor(acc[jj], 8);
    acc[jj] += __shfl_xor(acc[jj], 16);
    acc[jj] += __shfl_xor(acc[jj], 32);
  }
  if (g == 0) {
    float inv = 1.f / ((j ? p1 : p0) + 1e-16f);
    const float* bb = j ? blv : bmu;
    const int o = (lq & 3) * 8;              // channel within the 32-latent
    float r[8];
    #pragma unroll
    for (int jj = 0; jj < 8; ++jj) r[jj] = acc[jj] * inv + bb[o + jj];
    float4* dst = (float4*)(out + (size_t)j * N_NODES * LAT + (size_t)n * LAT + o);
    dst[0] = make_float4(r[0], r[1], r[2], r[3]);
    dst[1] = make_float4(r[4], r[5], r[6], r[7]);
  }
}

extern "C" void kernel_launch(void* const* d_in, const int* in_sizes, int n_in,
                              void* d_out, int out_size, void* d_ws, size_t ws_size,
                              hipStream_t stream) {
  const float* x        = (const float*)d_in[0];
  const int* ei         = (const int*)d_in[1];   // int32 per harness contract
  const float* W1       = (const float*)d_in[2];
  const float* att_src1 = (const float*)d_in[3];
  const float* att_dst1 = (const float*)d_in[4];
  const float* b1       = (const float*)d_in[5];
  const float* Wmu      = (const float*)d_in[6];
  const float* asmu     = (const float*)d_in[7];
  const float* admu     = (const float*)d_in[8];
  const float* bmu      = (const float*)d_in[9];
  const float* Wlv      = (const float*)d_in[10];
  const float* aslv     = (const float*)d_in[11];
  const float* adlv     = (const float*)d_in[12];
  const float* blv      = (const float*)d_in[13];
  float* out = (float*)d_out;

  // workspace layout (4-B units) — all 16-B-vector-loaded buffers 16-B aligned:
  //  [hact N*128 (dead slot, kept for layout stability) | a1 N*4 | a2 N*4 |
  //   h1b N*64(bf16 pairs) | h2b N*32 | Wb1g 4096 | Wb2g 2048 |
  //   counts N | cend N | cursor NBUCKET | csr N_B*BCAP]
  float* ws   = (float*)d_ws;
  float* hact = ws;                          // dead slot (proj2 fused away)
  float* a1   = hact + (size_t)N_NODES * 128;
  float* a2   = a1 + (size_t)N_NODES * 4;
  unsigned short* h1b = (unsigned short*)(a2 + (size_t)N_NODES * 4);
  unsigned short* h2b = h1b + (size_t)N_NODES * 128;
  unsigned short* Wb1g = h2b + (size_t)N_NODES * 64;   // byte off 46,400,000 (16-aligned)
  unsigned short* Wb2g = Wb1g + 16384;                  // +32 KB (16-aligned)
  int* counts = (int*)(Wb2g + 8192);
  int* cend   = counts + N_NODES;
  int* cursor = cend + N_NODES;
  unsigned* csr = (unsigned*)(cursor + NBUCKET);

  // prep: zero cursors + pack both weight matrices into B-frag layout
  prep_kernel<<<97, 256, 0, stream>>>(W1, Wmu, Wlv, cursor, Wb1g, Wb2g);

  // K1: bucket_scatter (416 blocks) || proj1+a1 (1563 blocks)
  k1_kernel<<<NSCAT + NPROJ1, 256, 0, stream>>>(
      ei, cursor, csr, x, Wb1g, att_src1, att_dst1, h1b, a1);
  bucket_fill_kernel<<<NBUCKET, 256, 0, stream>>>(cursor, csr, counts, cend);
  // fused: layer-1 aggregate + ELU + proj2 + a2 (hact stays in LDS)
  agg1_proj2_kernel<<<N_NODES / 16, 256, 0, stream>>>(
      counts, cend, csr, (const float4*)a1, (const unsigned*)h1b, b1,
      Wb2g, asmu, admu, aslv, adlv, h2b, a2);
  agg2_csr_kernel<<<N_NODES / 4, 256, 0, stream>>>(
      counts, cend, csr, (const float4*)a2, (const unsigned*)h2b, bmu, blv, out);
}